// Round 2
// baseline (8764.905 us; speedup 1.0000x reference)
//
#include <hip/hip_runtime.h>
#include <math.h>

typedef unsigned short u16;
typedef __attribute__((ext_vector_type(8))) short short8;
typedef __attribute__((ext_vector_type(8))) u16 ushort8_t;
typedef __attribute__((ext_vector_type(4))) u16 ushort4_t;
typedef __attribute__((ext_vector_type(4))) float f32x4;

#define BB 2
#define TT 1024
#define EE 768
#define HH 12
#define HSZ 64
#define LL 12
#define FF 3072
#define VV 50257
#define VPAD 50304   // VV padded to multiple of 128 (tile rows, avoids load guards)
#define MM 2048      // B*T rows
#define NQKV 2304    // fused q|k|v output width

__device__ __forceinline__ float bf2f(u16 u) {
    union { unsigned int i; float f; } c;
    c.i = ((unsigned int)u) << 16;
    return c.f;
}
__device__ __forceinline__ u16 f2bf(float f) {
    unsigned int u = __float_as_uint(f);
    unsigned int r = (u + 0x7FFFu + ((u >> 16) & 1u)) >> 16;
    return (u16)r;
}

__device__ __forceinline__ void gload_lds16(const void* g, void* l) {
    __builtin_amdgcn_global_load_lds(
        (const __attribute__((address_space(1))) unsigned int*)g,
        (__attribute__((address_space(3))) unsigned int*)l,
        16, 0, 0);
}

// ------------------------------------------------------------ weight precast
// fp32 -> bf16, per-layer strided dst (for qkv fusion). grid: (X, nLayers)
__global__ __launch_bounds__(256)
void cast_kernel(const float* __restrict__ src, u16* __restrict__ dst,
                 long perLayer, long dstStride)
{
    long layer = blockIdx.y;
    const float* s = src + layer * perLayer;
    u16* d = dst + layer * dstStride;
    long step = (long)gridDim.x * blockDim.x * 4;
    for (long i = ((long)blockIdx.x * blockDim.x + threadIdx.x) * 4;
         i < perLayer; i += step) {
        float4 v = *reinterpret_cast<const float4*>(s + i);
        ushort4_t o;
        o[0] = f2bf(v.x); o[1] = f2bf(v.y); o[2] = f2bf(v.z); o[3] = f2bf(v.w);
        *reinterpret_cast<ushort4_t*>(d + i) = o;
    }
}

// ---------------------------------------------------------------- embedding
__global__ void embed_kernel(const int* __restrict__ x, const float* __restrict__ tok,
                             const float* __restrict__ pos, float* __restrict__ h,
                             u16* __restrict__ hb)
{
    int row = blockIdx.x;
    int t = row & (TT - 1);
    int id = x[row];
    const float* tr = tok + (size_t)id * EE;
    const float* pr = pos + (size_t)t * EE;
    for (int i = threadIdx.x; i < EE; i += blockDim.x) {
        float v = tr[i] + pr[i];
        h[(size_t)row * EE + i] = v;
        hb[(size_t)row * EE + i] = f2bf(v);
    }
}

// ---------------------------------------------------------------- add + LN
__global__ __launch_bounds__(256)
void add_ln_kernel(const float* __restrict__ hin, const float* __restrict__ add,
                   const float* __restrict__ w, const float* __restrict__ bias,
                   float* __restrict__ hout, u16* __restrict__ hbout)
{
    int lane = threadIdx.x & 63, wv = threadIdx.x >> 6;
    int row = blockIdx.x * 4 + wv;
    const float* hp = hin + (size_t)row * EE;
    float x[12];
    float s = 0.f;
#pragma unroll
    for (int c = 0; c < 3; ++c) {
        float4 hv = *reinterpret_cast<const float4*>(hp + c * 256 + lane * 4);
        if (add) {
            float4 av = *reinterpret_cast<const float4*>(add + (size_t)row * EE + c * 256 + lane * 4);
            hv.x += av.x; hv.y += av.y; hv.z += av.z; hv.w += av.w;
        }
        x[c * 4 + 0] = hv.x; x[c * 4 + 1] = hv.y; x[c * 4 + 2] = hv.z; x[c * 4 + 3] = hv.w;
        s += hv.x + hv.y + hv.z + hv.w;
    }
#pragma unroll
    for (int o = 32; o > 0; o >>= 1) s += __shfl_xor(s, o);
    float mu = s * (1.0f / EE);
    float vs = 0.f;
#pragma unroll
    for (int i = 0; i < 12; ++i) { float d = x[i] - mu; vs += d * d; }
#pragma unroll
    for (int o = 32; o > 0; o >>= 1) vs += __shfl_xor(vs, o);
    float inv = 1.0f / sqrtf(vs * (1.0f / EE) + 1e-5f);
#pragma unroll
    for (int c = 0; c < 3; ++c) {
        int col = c * 256 + lane * 4;
        float4 wv4 = *reinterpret_cast<const float4*>(w + col);
        float4 bv4 = *reinterpret_cast<const float4*>(bias + col);
        float4 o;
        o.x = (x[c * 4 + 0] - mu) * inv * wv4.x + bv4.x;
        o.y = (x[c * 4 + 1] - mu) * inv * wv4.y + bv4.y;
        o.z = (x[c * 4 + 2] - mu) * inv * wv4.z + bv4.z;
        o.w = (x[c * 4 + 3] - mu) * inv * wv4.w + bv4.w;
        *reinterpret_cast<float4*>(hout + (size_t)row * EE + col) = o;
        ushort4_t ob;
        ob[0] = f2bf(o.x); ob[1] = f2bf(o.y); ob[2] = f2bf(o.z); ob[3] = f2bf(o.w);
        *reinterpret_cast<ushort4_t*>(hbout + (size_t)row * EE + col) = ob;
    }
}

// ---------------------------------------------------------------- GEMM
// C[M,N] = A[M,K](bf16) * W[N,K](bf16)^T  (+bias, +act)
// m97 structure: 128x128 tile, BK=64, global_load_lds width-16, linear LDS.
// M-fastest grid: blockIdx.x = M tile (B-tile shared by consecutive blocks).
#define BM 128
#define BN 128
#define BK 64

enum { EPI_GELU_BF16 = 1, EPI_BIAS_F32 = 2, EPI_F32 = 3 };

template<int EPI, bool NGUARD>
__global__ __launch_bounds__(256, 2)
void gemm_kernel(const u16* __restrict__ A, const u16* __restrict__ Bw,
                 const float* __restrict__ bias, void* __restrict__ Cout,
                 int Ndim, int Kdim)
{
    __shared__ u16 As[BM * BK];
    __shared__ u16 Bs[BN * BK];
    const int tid = threadIdx.x;
    const int lane = tid & 63;
    const int wid = tid >> 6;
    const int wm = wid >> 1, wn = wid & 1;
    const int rowBase = blockIdx.x * BM;
    const int colBase = blockIdx.y * BN;

    // staging geometry: one gload_lds16 = 1024B = 8 rows of 64 bf16.
    // wave wid, instr i covers rows r0=(wid*4+i)*8; lane l -> row r0+(l>>3), col (l&7)*8
    const int srow = lane >> 3;
    const int scol = (lane & 7) * 8;

    f32x4 acc[4][4] = {};

    for (int k0 = 0; k0 < Kdim; k0 += BK) {
#pragma unroll
        for (int i = 0; i < 4; ++i) {
            int r0 = (wid * 4 + i) * 8;
            gload_lds16(A + (size_t)(rowBase + r0 + srow) * Kdim + k0 + scol,
                        As + r0 * BK);
        }
#pragma unroll
        for (int i = 0; i < 4; ++i) {
            int r0 = (wid * 4 + i) * 8;
            gload_lds16(Bw + (size_t)(colBase + r0 + srow) * Kdim + k0 + scol,
                        Bs + r0 * BK);
        }
        __syncthreads();   // compiler drains vmcnt before s_barrier
#pragma unroll
        for (int kk = 0; kk < BK; kk += 32) {
            short8 af[4], bfr[4];
            int kcol = kk + (lane >> 4) * 8;
#pragma unroll
            for (int mi = 0; mi < 4; ++mi)
                af[mi] = *reinterpret_cast<const short8*>(
                    &As[(wm * 64 + mi * 16 + (lane & 15)) * BK + kcol]);
#pragma unroll
            for (int ni = 0; ni < 4; ++ni)
                bfr[ni] = *reinterpret_cast<const short8*>(
                    &Bs[(wn * 64 + ni * 16 + (lane & 15)) * BK + kcol]);
#pragma unroll
            for (int mi = 0; mi < 4; ++mi)
#pragma unroll
                for (int ni = 0; ni < 4; ++ni)
                    acc[mi][ni] = __builtin_amdgcn_mfma_f32_16x16x32_bf16(
                        af[mi], bfr[ni], acc[mi][ni], 0, 0, 0);
        }
        __syncthreads();
    }

    // epilogue: D row=(lane>>4)*4+r, col=lane&15  [m89-verified]
#pragma unroll
    for (int mi = 0; mi < 4; ++mi) {
#pragma unroll
        for (int ni = 0; ni < 4; ++ni) {
#pragma unroll
            for (int r = 0; r < 4; ++r) {
                int row = rowBase + wm * 64 + mi * 16 + (lane >> 4) * 4 + r;
                int col = colBase + wn * 64 + ni * 16 + (lane & 15);
                if (NGUARD && col >= Ndim) continue;
                float v = acc[mi][ni][r];
                if (EPI == EPI_GELU_BF16) { v += bias[col]; v = 0.5f * v * (1.0f + erff(v * 0.70710678f)); }
                if (EPI == EPI_BIAS_F32)  { v += bias[col]; }
                size_t idx = (size_t)row * Ndim + col;
                if (EPI == EPI_GELU_BF16)
                    ((u16*)Cout)[idx] = f2bf(v);
                else
                    ((float*)Cout)[idx] = v;
            }
        }
    }
}

// ---------------------------------------------------------------- attention
// out[b,s,h,:] = sum_{t<=s} softmax_t(k[b,s]·q[b,t]*scale) * v[b,t]
// qkv fused layout: qkv[b*T+t][2304], q=cols 0..767, k=+768, v=+1536 (f32)
__global__ __launch_bounds__(256)
void attn_kernel(const float* __restrict__ qkv, float* __restrict__ aout)
{
    __shared__ float p_lds[4][TT];
    int lane = threadIdx.x & 63, wv = threadIdx.x >> 6;
    int s = blockIdx.x * 4 + wv;
    int bh = blockIdx.y;
    int b = bh / HH, h = bh % HH;
    const float scale = 0.036084392f;  // 1/sqrt(768)
    size_t base = (size_t)b * TT * NQKV + h * HSZ;
    const float* q = qkv + base;
    const float* k = qkv + base + EE;
    const float* v = qkv + base + 2 * EE;

    // k[s] row -> registers
    float kf[64];
    {
        const float4* kp = reinterpret_cast<const float4*>(k + (size_t)s * NQKV);
#pragma unroll
        for (int c = 0; c < 16; ++c) {
            float4 kv = kp[c];
            kf[4 * c + 0] = kv.x; kf[4 * c + 1] = kv.y;
            kf[4 * c + 2] = kv.z; kf[4 * c + 3] = kv.w;
        }
    }

    // phase 1: scores -> LDS, track max
    float mx = -INFINITY;
    int jmax = s >> 6;
    for (int j = 0; j <= jmax; ++j) {
        int t = j * 64 + lane;
        float sc = -INFINITY;
        if (t <= s) {
            const float4* qp = reinterpret_cast<const float4*>(q + (size_t)t * NQKV);
            float acc = 0.f;
#pragma unroll
            for (int c = 0; c < 16; ++c) {
                float4 qv = qp[c];
                acc += kf[4 * c + 0] * qv.x + kf[4 * c + 1] * qv.y
                     + kf[4 * c + 2] * qv.z + kf[4 * c + 3] * qv.w;
            }
            sc = acc * scale;
        }
        p_lds[wv][j * 64 + lane] = sc;
        mx = fmaxf(mx, sc);
    }
#pragma unroll
    for (int o = 32; o > 0; o >>= 1) mx = fmaxf(mx, __shfl_xor(mx, o));

    float sum = 0.f;
    for (int t = lane; t <= s; t += 64) {
        float val = __expf(p_lds[wv][t] - mx);
        sum += val;
        p_lds[wv][t] = val;
    }
#pragma unroll
    for (int o = 32; o > 0; o >>= 1) sum += __shfl_xor(sum, o);
    float inv = 1.0f / sum;

    // phase 2: O[d=lane] = sum_t p[t] * v[t,d]
    float O = 0.f;
    int nfull = (s + 1) & ~3;
    int t = 0;
    for (; t < nfull; t += 4) {
        float4 pv = *reinterpret_cast<const float4*>(&p_lds[wv][t]);
        O += pv.x * v[(size_t)(t + 0) * NQKV + lane];
        O += pv.y * v[(size_t)(t + 1) * NQKV + lane];
        O += pv.z * v[(size_t)(t + 2) * NQKV + lane];
        O += pv.w * v[(size_t)(t + 3) * NQKV + lane];
    }
    for (; t <= s; ++t) O += p_lds[wv][t] * v[(size_t)t * NQKV + lane];

    size_t obase = (size_t)b * TT * EE + h * HSZ;
    aout[obase + (size_t)s * EE + lane] = O * inv;
}

// ---------------------------------------------------------------- driver
extern "C" void kernel_launch(void* const* d_in, const int* in_sizes, int n_in,
                              void* d_out, int out_size, void* d_ws, size_t ws_size,
                              hipStream_t stream)
{
    const int*   x    = (const int*)d_in[0];
    const float* tok  = (const float*)d_in[1];
    const float* pos  = (const float*)d_in[2];
    const float* qW   = (const float*)d_in[3];
    const float* kW   = (const float*)d_in[4];
    const float* vW   = (const float*)d_in[5];
    const float* ln1w = (const float*)d_in[6];
    const float* ln1b = (const float*)d_in[7];
    const float* fc1w = (const float*)d_in[8];
    const float* fc1b = (const float*)d_in[9];
    const float* fc2w = (const float*)d_in[10];
    const float* fc2b = (const float*)d_in[11];
    const float* ln2w = (const float*)d_in[12];
    const float* ln2b = (const float*)d_in[13];
    const float* lnfw = (const float*)d_in[14];
    const float* lnfb = (const float*)d_in[15];
    const float* lmw  = (const float*)d_in[16];
    float* out = (float*)d_out;

    char* ws = (char*)d_ws;
    u16* wqkv = (u16*)ws;  ws += (size_t)LL * NQKV * EE * 2;      // 42.5 MB
    u16* wfc1 = (u16*)ws;  ws += (size_t)LL * FF * EE * 2;        // 56.6 MB
    u16* wfc2 = (u16*)ws;  ws += (size_t)LL * EE * FF * 2;        // 56.6 MB
    u16* wlm  = (u16*)ws;  ws += (size_t)VPAD * EE * 2;           // 77.3 MB (padded)
    float* h    = (float*)ws; ws += (size_t)MM * EE * 4;
    float* tmp  = (float*)ws; ws += (size_t)MM * EE * 4;
    float* qkvb = (float*)ws; ws += (size_t)MM * NQKV * 4;        // 18.9 MB
    u16* hb = (u16*)ws;       ws += (size_t)MM * EE * 2;
    u16* mb = (u16*)ws;       ws += (size_t)MM * FF * 2;

    dim3 blk(256);

    // --- weight precast (fp32 -> bf16), qkv fused per layer
    cast_kernel<<<dim3(512, LL), blk, 0, stream>>>(qW, wqkv,             (long)EE * EE, (long)NQKV * EE);
    cast_kernel<<<dim3(512, LL), blk, 0, stream>>>(kW, wqkv + EE * EE,   (long)EE * EE, (long)NQKV * EE);
    cast_kernel<<<dim3(512, LL), blk, 0, stream>>>(vW, wqkv + 2 * EE * EE, (long)EE * EE, (long)NQKV * EE);
    cast_kernel<<<dim3(2048, LL), blk, 0, stream>>>(fc1w, wfc1, (long)FF * EE, (long)FF * EE);
    cast_kernel<<<dim3(2048, LL), blk, 0, stream>>>(fc2w, wfc2, (long)EE * FF, (long)EE * FF);
    cast_kernel<<<dim3(4096, 1),  blk, 0, stream>>>(lmw,  wlm,  (long)VV * EE, (long)VV * EE);

    embed_kernel<<<MM, blk, 0, stream>>>(x, tok, pos, h, hb);

    dim3 gQKV(MM / BM, NQKV / BN);   // 16 x 18
    dim3 gF1(MM / BM, FF / BN);      // 16 x 24
    dim3 gF2(MM / BM, EE / BN);      // 16 x 6
    dim3 gV(MM / BM, VPAD / BN);     // 16 x 393
    dim3 gAttn(TT / 4, BB * HH);

    for (int l = 0; l < LL; ++l) {
        gemm_kernel<EPI_F32, false><<<gQKV, blk, 0, stream>>>(
            hb, wqkv + (size_t)l * NQKV * EE, nullptr, qkvb, NQKV, EE);
        attn_kernel<<<gAttn, blk, 0, stream>>>(qkvb, tmp);
        add_ln_kernel<<<MM / 4, blk, 0, stream>>>(h, tmp, ln1w + l * EE, ln1b + l * EE, h, hb);
        gemm_kernel<EPI_GELU_BF16, false><<<gF1, blk, 0, stream>>>(
            hb, wfc1 + (size_t)l * FF * EE, fc1b + (size_t)l * FF, mb, FF, EE);
        gemm_kernel<EPI_BIAS_F32, false><<<gF2, blk, 0, stream>>>(
            mb, wfc2 + (size_t)l * EE * FF, fc2b + (size_t)l * EE, tmp, EE, FF);
        add_ln_kernel<<<MM / 4, blk, 0, stream>>>(h, tmp, ln2w + l * EE, ln2b + l * EE, h, hb);
    }
    add_ln_kernel<<<MM / 4, blk, 0, stream>>>(h, nullptr, lnfw, lnfb, h, hb);
    gemm_kernel<EPI_F32, true><<<gV, blk, 0, stream>>>(hb, wlm, nullptr, out, VV, EE);
}

// Round 3
// 2504.512 us; speedup vs baseline: 3.4996x; 3.4996x over previous
//
#include <hip/hip_runtime.h>
#include <math.h>

typedef unsigned short u16;
typedef __attribute__((ext_vector_type(8))) short short8;
typedef __attribute__((ext_vector_type(8))) u16 ushort8_t;
typedef __attribute__((ext_vector_type(4))) u16 ushort4_t;
typedef __attribute__((ext_vector_type(4))) float f32x4;

#define BB 2
#define TT 1024
#define EE 768
#define HH 12
#define HSZ 64
#define LL 12
#define FF 3072
#define VV 50257
#define VPAD 50304
#define MM 2048
#define NQKV 2304
#define QKW 1536     // q|k bf16 buffer width

__device__ __forceinline__ float bf2f(u16 u) {
    union { unsigned int i; float f; } c;
    c.i = ((unsigned int)u) << 16;
    return c.f;
}
__device__ __forceinline__ u16 f2bf(float f) {
    unsigned int u = __float_as_uint(f);
    unsigned int r = (u + 0x7FFFu + ((u >> 16) & 1u)) >> 16;
    return (u16)r;
}

__device__ __forceinline__ void gload_lds16(const void* g, void* l) {
    __builtin_amdgcn_global_load_lds(
        (const __attribute__((address_space(1))) unsigned int*)g,
        (__attribute__((address_space(3))) unsigned int*)l,
        16, 0, 0);
}

// ------------------------------------------------------------ weight precast
__global__ __launch_bounds__(256)
void cast_kernel(const float* __restrict__ src, u16* __restrict__ dst,
                 long perLayer, long dstStride)
{
    long layer = blockIdx.y;
    const float* s = src + layer * perLayer;
    u16* d = dst + layer * dstStride;
    long step = (long)gridDim.x * blockDim.x * 4;
    for (long i = ((long)blockIdx.x * blockDim.x + threadIdx.x) * 4;
         i < perLayer; i += step) {
        float4 v = *reinterpret_cast<const float4*>(s + i);
        ushort4_t o;
        o[0] = f2bf(v.x); o[1] = f2bf(v.y); o[2] = f2bf(v.z); o[3] = f2bf(v.w);
        *reinterpret_cast<ushort4_t*>(d + i) = o;
    }
}

// ---------------------------------------------------------------- embedding
__global__ void embed_kernel(const int* __restrict__ x, const float* __restrict__ tok,
                             const float* __restrict__ pos, float* __restrict__ h,
                             u16* __restrict__ hb)
{
    int row = blockIdx.x;
    int t = row & (TT - 1);
    int id = x[row];
    const float* tr = tok + (size_t)id * EE;
    const float* pr = pos + (size_t)t * EE;
    for (int i = threadIdx.x; i < EE; i += blockDim.x) {
        float v = tr[i] + pr[i];
        h[(size_t)row * EE + i] = v;
        hb[(size_t)row * EE + i] = f2bf(v);
    }
}

// ---------------------------------------------------------------- add + LN
__global__ __launch_bounds__(256)
void add_ln_kernel(const float* __restrict__ hin, const float* __restrict__ add,
                   const float* __restrict__ w, const float* __restrict__ bias,
                   float* __restrict__ hout, u16* __restrict__ hbout)
{
    int lane = threadIdx.x & 63, wv = threadIdx.x >> 6;
    int row = blockIdx.x * 4 + wv;
    const float* hp = hin + (size_t)row * EE;
    float x[12];
    float s = 0.f;
#pragma unroll
    for (int c = 0; c < 3; ++c) {
        float4 hv = *reinterpret_cast<const float4*>(hp + c * 256 + lane * 4);
        if (add) {
            float4 av = *reinterpret_cast<const float4*>(add + (size_t)row * EE + c * 256 + lane * 4);
            hv.x += av.x; hv.y += av.y; hv.z += av.z; hv.w += av.w;
        }
        x[c * 4 + 0] = hv.x; x[c * 4 + 1] = hv.y; x[c * 4 + 2] = hv.z; x[c * 4 + 3] = hv.w;
        s += hv.x + hv.y + hv.z + hv.w;
    }
#pragma unroll
    for (int o = 32; o > 0; o >>= 1) s += __shfl_xor(s, o);
    float mu = s * (1.0f / EE);
    float vs = 0.f;
#pragma unroll
    for (int i = 0; i < 12; ++i) { float d = x[i] - mu; vs += d * d; }
#pragma unroll
    for (int o = 32; o > 0; o >>= 1) vs += __shfl_xor(vs, o);
    float inv = 1.0f / sqrtf(vs * (1.0f / EE) + 1e-5f);
#pragma unroll
    for (int c = 0; c < 3; ++c) {
        int col = c * 256 + lane * 4;
        float4 wv4 = *reinterpret_cast<const float4*>(w + col);
        float4 bv4 = *reinterpret_cast<const float4*>(bias + col);
        float4 o;
        o.x = (x[c * 4 + 0] - mu) * inv * wv4.x + bv4.x;
        o.y = (x[c * 4 + 1] - mu) * inv * wv4.y + bv4.y;
        o.z = (x[c * 4 + 2] - mu) * inv * wv4.z + bv4.z;
        o.w = (x[c * 4 + 3] - mu) * inv * wv4.w + bv4.w;
        *reinterpret_cast<float4*>(hout + (size_t)row * EE + col) = o;
        ushort4_t ob;
        ob[0] = f2bf(o.x); ob[1] = f2bf(o.y); ob[2] = f2bf(o.z); ob[3] = f2bf(o.w);
        *reinterpret_cast<ushort4_t*>(hbout + (size_t)row * EE + col) = ob;
    }
}

// ---------------------------------------------------------------- GEMM
#define BM 128
#define BN 128
#define BK 64

enum { EPI_GELU_BF16 = 1, EPI_BIAS_F32 = 2, EPI_F32 = 3, EPI_QKV = 4 };

template<int EPI, bool NGUARD>
__global__ __launch_bounds__(256, 2)
void gemm_kernel(const u16* __restrict__ A, const u16* __restrict__ Bw,
                 const float* __restrict__ bias, void* __restrict__ Cout,
                 void* __restrict__ vTout, int Ndim, int Kdim)
{
    __shared__ u16 As[BM * BK];
    __shared__ u16 Bs[BN * BK];
    const int tid = threadIdx.x;
    const int lane = tid & 63;
    const int wid = tid >> 6;
    const int wm = wid >> 1, wn = wid & 1;
    const int rowBase = blockIdx.x * BM;
    const int colBase = blockIdx.y * BN;

    const int srow = lane >> 3;
    const int scol = (lane & 7) * 8;

    f32x4 acc[4][4] = {};

    for (int k0 = 0; k0 < Kdim; k0 += BK) {
#pragma unroll
        for (int i = 0; i < 4; ++i) {
            int r0 = (wid * 4 + i) * 8;
            gload_lds16(A + (size_t)(rowBase + r0 + srow) * Kdim + k0 + scol,
                        As + r0 * BK);
        }
#pragma unroll
        for (int i = 0; i < 4; ++i) {
            int r0 = (wid * 4 + i) * 8;
            gload_lds16(Bw + (size_t)(colBase + r0 + srow) * Kdim + k0 + scol,
                        Bs + r0 * BK);
        }
        __syncthreads();
#pragma unroll
        for (int kk = 0; kk < BK; kk += 32) {
            short8 af[4], bfr[4];
            int kcol = kk + (lane >> 4) * 8;
#pragma unroll
            for (int mi = 0; mi < 4; ++mi)
                af[mi] = *reinterpret_cast<const short8*>(
                    &As[(wm * 64 + mi * 16 + (lane & 15)) * BK + kcol]);
#pragma unroll
            for (int ni = 0; ni < 4; ++ni)
                bfr[ni] = *reinterpret_cast<const short8*>(
                    &Bs[(wn * 64 + ni * 16 + (lane & 15)) * BK + kcol]);
#pragma unroll
            for (int mi = 0; mi < 4; ++mi)
#pragma unroll
                for (int ni = 0; ni < 4; ++ni)
                    acc[mi][ni] = __builtin_amdgcn_mfma_f32_16x16x32_bf16(
                        af[mi], bfr[ni], acc[mi][ni], 0, 0, 0);
        }
        __syncthreads();
    }

#pragma unroll
    for (int mi = 0; mi < 4; ++mi) {
#pragma unroll
        for (int ni = 0; ni < 4; ++ni) {
#pragma unroll
            for (int r = 0; r < 4; ++r) {
                int row = rowBase + wm * 64 + mi * 16 + (lane >> 4) * 4 + r;
                int col = colBase + wn * 64 + ni * 16 + (lane & 15);
                if (NGUARD && col >= Ndim) continue;
                float v = acc[mi][ni][r];
                if (EPI == EPI_GELU_BF16) { v += bias[col]; v = 0.5f * v * (1.0f + erff(v * 0.70710678f)); }
                if (EPI == EPI_BIAS_F32)  { v += bias[col]; }
                if (EPI == EPI_QKV) {
                    // q|k -> qkb[row][col] bf16 ; v -> vT[b][h][d][t] bf16
                    if (col < QKW)
                        ((u16*)Cout)[(size_t)row * QKW + col] = f2bf(v);
                    else {
                        int hd = col - QKW;                     // h*64+d, 0..767
                        ((u16*)vTout)[((size_t)(row >> 10) * EE + hd) * TT + (row & (TT - 1))] = f2bf(v);
                    }
                } else if (EPI == EPI_GELU_BF16) {
                    ((u16*)Cout)[(size_t)row * Ndim + col] = f2bf(v);
                } else {
                    ((float*)Cout)[(size_t)row * Ndim + col] = v;
                }
            }
        }
    }
}

// ---------------------------------------------------------------- flash attention (MFMA)
// out[b,s,h,:] = sum_{t<=s} softmax_t(k[s]·q[t]*scale) v[t]
// A-operand rows = k rows (s), B-operand rows = q rows (t). Causal over t<=s.
// Block: one (b,h), 64 s-rows, 4 waves x 16-row m-tiles. t-tiles of 64,
// Q and V^T tiles double-buffered in LDS (gload_lds, pre-swizzled source).
__global__ __launch_bounds__(256)
void attn_kernel(const u16* __restrict__ qkb, const u16* __restrict__ vT,
                 float* __restrict__ aout)
{
    __shared__ u16 Qs[2 * 64 * 64];   // [buf][t 64][d 64] (units XOR-swizzled)
    __shared__ u16 Vs[2 * 64 * 64];   // [buf][d 64][t 64]
    __shared__ u16 Ps[4 * 16 * 64];   // per-wave P tile [s 16][t 64]

    const int lane = threadIdx.x & 63;
    const int wv = threadIdx.x >> 6;
    const int js = blockIdx.x;        // s-tile
    const int s0 = js * 64;
    const int bh = blockIdx.y;
    const int b = bh / HH, h = bh % HH;
    const int bT = b * TT;
    const float scale = 0.036084392f; // 1/sqrt(768)

    // --- persistent K fragments (A operand): rows s0+wv*16+(lane&15)
    short8 af[2];
    {
        int srow = bT + s0 + wv * 16 + (lane & 15);
#pragma unroll
        for (int kk = 0; kk < 2; ++kk)
            af[kk] = *reinterpret_cast<const short8*>(
                qkb + (size_t)srow * QKW + EE + h * HSZ + kk * 32 + (lane >> 4) * 8);
    }

    // staging: wave wv covers LDS rows [wv*16, wv*16+16), 2 instrs of 8 rows
    const int lrow8 = lane >> 3;      // 0..7
    const int lu = lane & 7;          // 16B unit
#define STAGE_QV(jt, buf)                                                            \
    {                                                                                \
        int t0_ = (jt) * 64;                                                         \
        _Pragma("unroll")                                                            \
        for (int i_ = 0; i_ < 2; ++i_) {                                             \
            int R0_ = wv * 16 + i_ * 8;                                              \
            int row_ = R0_ + lrow8;                                                  \
            int g_ = lu ^ (row_ & 7);                                                \
            gload_lds16(qkb + (size_t)(bT + t0_ + row_) * QKW + h * HSZ + g_ * 8,    \
                        &Qs[(buf) * 4096 + R0_ * 64]);                               \
            gload_lds16(vT + ((size_t)(b * EE) + h * HSZ + row_) * TT + t0_ + g_ * 8,\
                        &Vs[(buf) * 4096 + R0_ * 64]);                               \
        }                                                                            \
    }

    STAGE_QV(0, 0)

    float m[4], l[4];
    f32x4 oacc[4] = {};
#pragma unroll
    for (int r = 0; r < 4; ++r) { m[r] = -INFINITY; l[r] = 0.f; }

    int cur = 0;
    for (int jt = 0; jt <= js; ++jt) {
        __syncthreads();              // drains vmcnt: buf[cur] ready, prev reads done
        if (jt < js) STAGE_QV(jt + 1, cur ^ 1)

        const u16* Qb = &Qs[cur * 4096];
        const u16* Vb = &Vs[cur * 4096];

        // ---- scores: 16 s x 64 t
        f32x4 sc[4] = {};
#pragma unroll
        for (int ni = 0; ni < 4; ++ni) {
            int trow = ni * 16 + (lane & 15);
#pragma unroll
            for (int kk = 0; kk < 2; ++kk) {
                int g = kk * 4 + (lane >> 4);
                short8 bq = *reinterpret_cast<const short8*>(
                    &Qb[trow * 64 + ((g ^ (trow & 7)) * 8)]);
                sc[ni] = __builtin_amdgcn_mfma_f32_16x16x32_bf16(af[kk], bq, sc[ni], 0, 0, 0);
            }
        }

        // ---- scale + causal mask (diagonal tile only)
        const bool diag = (jt == js);
#pragma unroll
        for (int ni = 0; ni < 4; ++ni)
#pragma unroll
            for (int r = 0; r < 4; ++r) {
                float sv = sc[ni][r] * scale;
                if (diag && (ni * 16 + (lane & 15)) > (wv * 16 + (lane >> 4) * 4 + r))
                    sv = -1e30f;
                sc[ni][r] = sv;
            }

        // ---- online softmax per s-row (row = (lane>>4)*4+r, cols across lane&15)
        f32x4 pexp[4];
#pragma unroll
        for (int r = 0; r < 4; ++r) {
            float rm = fmaxf(fmaxf(sc[0][r], sc[1][r]), fmaxf(sc[2][r], sc[3][r]));
#pragma unroll
            for (int o = 1; o < 16; o <<= 1) rm = fmaxf(rm, __shfl_xor(rm, o));
            float mnew = fmaxf(m[r], rm);
            float alpha = __expf(m[r] - mnew);
            m[r] = mnew;
            float rs = 0.f;
#pragma unroll
            for (int ni = 0; ni < 4; ++ni) {
                float p = __expf(sc[ni][r] - mnew);
                pexp[ni][r] = p;
                rs += p;
            }
#pragma unroll
            for (int o = 1; o < 16; o <<= 1) rs += __shfl_xor(rs, o);
            l[r] = l[r] * alpha + rs;
#pragma unroll
            for (int dt = 0; dt < 4; ++dt) oacc[dt][r] *= alpha;
        }

        // ---- P -> LDS (bf16, swizzled), reshape to A-operand
#pragma unroll
        for (int ni = 0; ni < 4; ++ni)
#pragma unroll
            for (int r = 0; r < 4; ++r) {
                int sl = (lane >> 4) * 4 + r;
                int tl = ni * 16 + (lane & 15);
                Ps[wv * 1024 + sl * 64 + ((tl >> 3) ^ (sl & 7)) * 8 + (tl & 7)] = f2bf(pexp[ni][r]);
            }

        short8 pa[2];
#pragma unroll
        for (int kk = 0; kk < 2; ++kk) {
            int srow = lane & 15;
            int g = kk * 4 + (lane >> 4);
            pa[kk] = *reinterpret_cast<const short8*>(
                &Ps[wv * 1024 + srow * 64 + ((g ^ (srow & 7)) * 8)]);
        }

        // ---- O += P * V   (B rows = d, k = t)
#pragma unroll
        for (int dt = 0; dt < 4; ++dt) {
            int drow = dt * 16 + (lane & 15);
#pragma unroll
            for (int kk = 0; kk < 2; ++kk) {
                int g = kk * 4 + (lane >> 4);
                short8 bv = *reinterpret_cast<const short8*>(
                    &Vb[drow * 64 + ((g ^ (drow & 7)) * 8)]);
                oacc[dt] = __builtin_amdgcn_mfma_f32_16x16x32_bf16(pa[kk], bv, oacc[dt], 0, 0, 0);
            }
        }
        cur ^= 1;
    }

    // ---- output: O[s][d] / l
    float invl[4];
#pragma unroll
    for (int r = 0; r < 4; ++r) invl[r] = 1.0f / l[r];
#pragma unroll
    for (int dt = 0; dt < 4; ++dt)
#pragma unroll
        for (int r = 0; r < 4; ++r) {
            int sg = s0 + wv * 16 + (lane >> 4) * 4 + r;
            aout[(size_t)(bT + sg) * EE + h * HSZ + dt * 16 + (lane & 15)] =
                oacc[dt][r] * invl[r];
        }
}

// ---------------------------------------------------------------- driver
extern "C" void kernel_launch(void* const* d_in, const int* in_sizes, int n_in,
                              void* d_out, int out_size, void* d_ws, size_t ws_size,
                              hipStream_t stream)
{
    const int*   x    = (const int*)d_in[0];
    const float* tok  = (const float*)d_in[1];
    const float* pos  = (const float*)d_in[2];
    const float* qW   = (const float*)d_in[3];
    const float* kW   = (const float*)d_in[4];
    const float* vW   = (const float*)d_in[5];
    const float* ln1w = (const float*)d_in[6];
    const float* ln1b = (const float*)d_in[7];
    const float* fc1w = (const float*)d_in[8];
    const float* fc1b = (const float*)d_in[9];
    const float* fc2w = (const float*)d_in[10];
    const float* fc2b = (const float*)d_in[11];
    const float* ln2w = (const float*)d_in[12];
    const float* ln2b = (const float*)d_in[13];
    const float* lnfw = (const float*)d_in[14];
    const float* lnfb = (const float*)d_in[15];
    const float* lmw  = (const float*)d_in[16];
    float* out = (float*)d_out;

    char* ws = (char*)d_ws;
    u16* wqkv = (u16*)ws;  ws += (size_t)LL * NQKV * EE * 2;
    u16* wfc1 = (u16*)ws;  ws += (size_t)LL * FF * EE * 2;
    u16* wfc2 = (u16*)ws;  ws += (size_t)LL * EE * FF * 2;
    u16* wlm  = (u16*)ws;  ws += (size_t)VPAD * EE * 2;
    float* h    = (float*)ws; ws += (size_t)MM * EE * 4;
    float* tmp  = (float*)ws; ws += (size_t)MM * EE * 4;
    u16* qkb = (u16*)ws;      ws += (size_t)MM * QKW * 2;
    u16* vTb = (u16*)ws;      ws += (size_t)BB * EE * TT * 2;
    u16* hb  = (u16*)ws;      ws += (size_t)MM * EE * 2;
    u16* mb  = (u16*)ws;      ws += (size_t)MM * FF * 2;

    dim3 blk(256);

    cast_kernel<<<dim3(512, LL), blk, 0, stream>>>(qW, wqkv,               (long)EE * EE, (long)NQKV * EE);
    cast_kernel<<<dim3(512, LL), blk, 0, stream>>>(kW, wqkv + EE * EE,     (long)EE * EE, (long)NQKV * EE);
    cast_kernel<<<dim3(512, LL), blk, 0, stream>>>(vW, wqkv + 2 * EE * EE, (long)EE * EE, (long)NQKV * EE);
    cast_kernel<<<dim3(2048, LL), blk, 0, stream>>>(fc1w, wfc1, (long)FF * EE, (long)FF * EE);
    cast_kernel<<<dim3(2048, LL), blk, 0, stream>>>(fc2w, wfc2, (long)EE * FF, (long)EE * FF);
    cast_kernel<<<dim3(4096, 1),  blk, 0, stream>>>(lmw,  wlm,  (long)VV * EE, (long)VV * EE);

    embed_kernel<<<MM, blk, 0, stream>>>(x, tok, pos, h, hb);

    dim3 gQKV(MM / BM, NQKV / BN);
    dim3 gF1(MM / BM, FF / BN);
    dim3 gF2(MM / BM, EE / BN);
    dim3 gV(MM / BM, VPAD / BN);
    dim3 gAttn(TT / 64, BB * HH);

    for (int l = 0; l < LL; ++l) {
        gemm_kernel<EPI_QKV, false><<<gQKV, blk, 0, stream>>>(
            hb, wqkv + (size_t)l * NQKV * EE, nullptr, qkb, vTb, NQKV, EE);
        attn_kernel<<<gAttn, blk, 0, stream>>>(qkb, vTb, tmp);
        add_ln_kernel<<<MM / 4, blk, 0, stream>>>(h, tmp, ln1w + l * EE, ln1b + l * EE, h, hb);
        gemm_kernel<EPI_GELU_BF16, false><<<gF1, blk, 0, stream>>>(
            hb, wfc1 + (size_t)l * FF * EE, fc1b + (size_t)l * FF, mb, nullptr, FF, EE);
        gemm_kernel<EPI_BIAS_F32, false><<<gF2, blk, 0, stream>>>(
            mb, wfc2 + (size_t)l * EE * FF, fc2b + (size_t)l * EE, tmp, nullptr, EE, FF);
        add_ln_kernel<<<MM / 4, blk, 0, stream>>>(h, tmp, ln2w + l * EE, ln2b + l * EE, h, hb);
    }
    add_ln_kernel<<<MM / 4, blk, 0, stream>>>(h, nullptr, lnfw, lnfb, h, hb);
    gemm_kernel<EPI_F32, true><<<gV, blk, 0, stream>>>(hb, wlm, nullptr, out, nullptr, VV, EE);
}

// Round 4
// 2386.236 us; speedup vs baseline: 3.6731x; 1.0496x over previous
//
#include <hip/hip_runtime.h>
#include <math.h>

typedef unsigned short u16;
typedef __attribute__((ext_vector_type(8))) short short8;
typedef __attribute__((ext_vector_type(8))) u16 ushort8_t;
typedef __attribute__((ext_vector_type(4))) u16 ushort4_t;
typedef __attribute__((ext_vector_type(4))) float f32x4;

#define BB 2
#define TT 1024
#define EE 768
#define HH 12
#define HSZ 64
#define LL 12
#define FF 3072
#define VV 50257
#define VPAD 50304
#define MM 2048
#define NQKV 2304
#define QKW 1536     // q|k bf16 buffer width

__device__ __forceinline__ float bf2f(u16 u) {
    union { unsigned int i; float f; } c;
    c.i = ((unsigned int)u) << 16;
    return c.f;
}
__device__ __forceinline__ u16 f2bf(float f) {
    unsigned int u = __float_as_uint(f);
    unsigned int r = (u + 0x7FFFu + ((u >> 16) & 1u)) >> 16;
    return (u16)r;
}

__device__ __forceinline__ void gload_lds16(const void* g, void* l) {
    __builtin_amdgcn_global_load_lds(
        (const __attribute__((address_space(1))) unsigned int*)g,
        (__attribute__((address_space(3))) unsigned int*)l,
        16, 0, 0);
}

// bijective XCD-aware block remap (m204); requires gridX*gridY % 8 == 0 (all ours are)
__device__ __forceinline__ void xcd_swizzle(int& bx, int& by) {
    int nx = gridDim.x;
    int nwg = nx * gridDim.y;
    int orig = blockIdx.x + blockIdx.y * nx;
    int q = nwg >> 3, r = nwg & 7;
    int xcd = orig & 7, idx = orig >> 3;
    int nf = (xcd < r ? xcd * (q + 1) : r * (q + 1) + (xcd - r) * q) + idx;
    bx = nf % nx;
    by = nf / nx;
}

// ------------------------------------------------------------ weight precast
__global__ __launch_bounds__(256)
void cast_kernel(const float* __restrict__ src, u16* __restrict__ dst,
                 long perLayer, long dstStride)
{
    long layer = blockIdx.y;
    const float* s = src + layer * perLayer;
    u16* d = dst + layer * dstStride;
    long step = (long)gridDim.x * blockDim.x * 4;
    for (long i = ((long)blockIdx.x * blockDim.x + threadIdx.x) * 4;
         i < perLayer; i += step) {
        float4 v = *reinterpret_cast<const float4*>(s + i);
        ushort4_t o;
        o[0] = f2bf(v.x); o[1] = f2bf(v.y); o[2] = f2bf(v.z); o[3] = f2bf(v.w);
        *reinterpret_cast<ushort4_t*>(d + i) = o;
    }
}

// ---------------------------------------------------------------- embedding
__global__ void embed_kernel(const int* __restrict__ x, const float* __restrict__ tok,
                             const float* __restrict__ pos, float* __restrict__ h,
                             u16* __restrict__ hb)
{
    int row = blockIdx.x;
    int t = row & (TT - 1);
    int id = x[row];
    const float* tr = tok + (size_t)id * EE;
    const float* pr = pos + (size_t)t * EE;
    for (int i = threadIdx.x; i < EE; i += blockDim.x) {
        float v = tr[i] + pr[i];
        h[(size_t)row * EE + i] = v;
        hb[(size_t)row * EE + i] = f2bf(v);
    }
}

// ---------------------------------------------------------------- add + LN
__global__ __launch_bounds__(256)
void add_ln_kernel(const float* __restrict__ hin, const float* __restrict__ add,
                   const float* __restrict__ w, const float* __restrict__ bias,
                   float* __restrict__ hout, u16* __restrict__ hbout)
{
    int lane = threadIdx.x & 63, wv = threadIdx.x >> 6;
    int row = blockIdx.x * 4 + wv;
    const float* hp = hin + (size_t)row * EE;
    float x[12];
    float s = 0.f;
#pragma unroll
    for (int c = 0; c < 3; ++c) {
        float4 hv = *reinterpret_cast<const float4*>(hp + c * 256 + lane * 4);
        if (add) {
            float4 av = *reinterpret_cast<const float4*>(add + (size_t)row * EE + c * 256 + lane * 4);
            hv.x += av.x; hv.y += av.y; hv.z += av.z; hv.w += av.w;
        }
        x[c * 4 + 0] = hv.x; x[c * 4 + 1] = hv.y; x[c * 4 + 2] = hv.z; x[c * 4 + 3] = hv.w;
        s += hv.x + hv.y + hv.z + hv.w;
    }
#pragma unroll
    for (int o = 32; o > 0; o >>= 1) s += __shfl_xor(s, o);
    float mu = s * (1.0f / EE);
    float vs = 0.f;
#pragma unroll
    for (int i = 0; i < 12; ++i) { float d = x[i] - mu; vs += d * d; }
#pragma unroll
    for (int o = 32; o > 0; o >>= 1) vs += __shfl_xor(vs, o);
    float inv = 1.0f / sqrtf(vs * (1.0f / EE) + 1e-5f);
#pragma unroll
    for (int c = 0; c < 3; ++c) {
        int col = c * 256 + lane * 4;
        float4 wv4 = *reinterpret_cast<const float4*>(w + col);
        float4 bv4 = *reinterpret_cast<const float4*>(bias + col);
        float4 o;
        o.x = (x[c * 4 + 0] - mu) * inv * wv4.x + bv4.x;
        o.y = (x[c * 4 + 1] - mu) * inv * wv4.y + bv4.y;
        o.z = (x[c * 4 + 2] - mu) * inv * wv4.z + bv4.z;
        o.w = (x[c * 4 + 3] - mu) * inv * wv4.w + bv4.w;
        *reinterpret_cast<float4*>(hout + (size_t)row * EE + col) = o;
        ushort4_t ob;
        ob[0] = f2bf(o.x); ob[1] = f2bf(o.y); ob[2] = f2bf(o.z); ob[3] = f2bf(o.w);
        *reinterpret_cast<ushort4_t*>(hbout + (size_t)row * EE + col) = ob;
    }
}

// ---------------------------------------------------------------- GEMM
// 128x128 tile, BK=64, global_load_lds w16 with pre-swizzled source (T2/rule#21),
// XOR-swizzled fragment reads, bijective XCD block swizzle (T1).
#define BM 128
#define BN 128
#define BK 64

enum { EPI_GELU_BF16 = 1, EPI_BIAS_F32 = 2, EPI_F32 = 3, EPI_QKV = 4 };

template<int EPI, bool NGUARD>
__global__ __launch_bounds__(256, 2)
void gemm_kernel(const u16* __restrict__ A, const u16* __restrict__ Bw,
                 const float* __restrict__ bias, void* __restrict__ Cout,
                 void* __restrict__ vTout, int Ndim, int Kdim)
{
    __shared__ u16 As[BM * BK];
    __shared__ u16 Bs[BN * BK];
    const int tid = threadIdx.x;
    const int lane = tid & 63;
    const int wid = tid >> 6;
    const int wm = wid >> 1, wn = wid & 1;
    int bx, by;
    xcd_swizzle(bx, by);
    const int rowBase = bx * BM;
    const int colBase = by * BN;

    // staging: lane l of instr covers row r0+(l>>3); source unit XOR'd by row&7
    const int srow = lane >> 3;
    const int scol = ((lane & 7) ^ srow) * 8;   // pre-swizzled global source

    f32x4 acc[4][4] = {};

    for (int k0 = 0; k0 < Kdim; k0 += BK) {
#pragma unroll
        for (int i = 0; i < 4; ++i) {
            int r0 = (wid * 4 + i) * 8;
            gload_lds16(A + (size_t)(rowBase + r0 + srow) * Kdim + k0 + scol,
                        As + r0 * BK);
        }
#pragma unroll
        for (int i = 0; i < 4; ++i) {
            int r0 = (wid * 4 + i) * 8;
            gload_lds16(Bw + (size_t)(colBase + r0 + srow) * Kdim + k0 + scol,
                        Bs + r0 * BK);
        }
        __syncthreads();
        const int fr = lane & 15;       // fragment row within 16
        const int qd = lane >> 4;       // k-quadrant
#pragma unroll
        for (int kk = 0; kk < 2; ++kk) {
            short8 af[4], bfr[4];
            int g0 = kk * 4 + qd;                        // 16B unit before swizzle
            int goff = (g0 ^ (fr & 7)) * 8;              // swizzled element offset
#pragma unroll
            for (int mi = 0; mi < 4; ++mi)
                af[mi] = *reinterpret_cast<const short8*>(
                    &As[(wm * 64 + mi * 16 + fr) * BK + goff]);
#pragma unroll
            for (int ni = 0; ni < 4; ++ni)
                bfr[ni] = *reinterpret_cast<const short8*>(
                    &Bs[(wn * 64 + ni * 16 + fr) * BK + goff]);
#pragma unroll
            for (int mi = 0; mi < 4; ++mi)
#pragma unroll
                for (int ni = 0; ni < 4; ++ni)
                    acc[mi][ni] = __builtin_amdgcn_mfma_f32_16x16x32_bf16(
                        af[mi], bfr[ni], acc[mi][ni], 0, 0, 0);
        }
        __syncthreads();
    }

#pragma unroll
    for (int mi = 0; mi < 4; ++mi) {
#pragma unroll
        for (int ni = 0; ni < 4; ++ni) {
#pragma unroll
            for (int r = 0; r < 4; ++r) {
                int row = rowBase + wm * 64 + mi * 16 + (lane >> 4) * 4 + r;
                int col = colBase + wn * 64 + ni * 16 + (lane & 15);
                if (NGUARD && col >= Ndim) continue;
                float v = acc[mi][ni][r];
                if (EPI == EPI_GELU_BF16) { v += bias[col]; v = 0.5f * v * (1.0f + erff(v * 0.70710678f)); }
                if (EPI == EPI_BIAS_F32)  { v += bias[col]; }
                if (EPI == EPI_QKV) {
                    if (col < QKW)
                        ((u16*)Cout)[(size_t)row * QKW + col] = f2bf(v);
                    else {
                        int hd = col - QKW;
                        ((u16*)vTout)[((size_t)(row >> 10) * EE + hd) * TT + (row & (TT - 1))] = f2bf(v);
                    }
                } else if (EPI == EPI_GELU_BF16) {
                    ((u16*)Cout)[(size_t)row * Ndim + col] = f2bf(v);
                } else {
                    ((float*)Cout)[(size_t)row * Ndim + col] = v;
                }
            }
        }
    }
}

// ---------------------------------------------------------------- flash attention (MFMA)
__global__ __launch_bounds__(256)
void attn_kernel(const u16* __restrict__ qkb, const u16* __restrict__ vT,
                 float* __restrict__ aout)
{
    __shared__ u16 Qs[2 * 64 * 64];
    __shared__ u16 Vs[2 * 64 * 64];
    __shared__ u16 Ps[4 * 16 * 64];

    const int lane = threadIdx.x & 63;
    const int wv = threadIdx.x >> 6;
    const int js = blockIdx.x;
    const int s0 = js * 64;
    const int bh = blockIdx.y;
    const int b = bh / HH, h = bh % HH;
    const int bT = b * TT;
    const float scale = 0.036084392f;

    short8 af[2];
    {
        int srow = bT + s0 + wv * 16 + (lane & 15);
#pragma unroll
        for (int kk = 0; kk < 2; ++kk)
            af[kk] = *reinterpret_cast<const short8*>(
                qkb + (size_t)srow * QKW + EE + h * HSZ + kk * 32 + (lane >> 4) * 8);
    }

    const int lrow8 = lane >> 3;
    const int lu = lane & 7;
#define STAGE_QV(jt, buf)                                                            \
    {                                                                                \
        int t0_ = (jt) * 64;                                                         \
        _Pragma("unroll")                                                            \
        for (int i_ = 0; i_ < 2; ++i_) {                                             \
            int R0_ = wv * 16 + i_ * 8;                                              \
            int row_ = R0_ + lrow8;                                                  \
            int g_ = lu ^ (row_ & 7);                                                \
            gload_lds16(qkb + (size_t)(bT + t0_ + row_) * QKW + h * HSZ + g_ * 8,    \
                        &Qs[(buf) * 4096 + R0_ * 64]);                               \
            gload_lds16(vT + ((size_t)(b * EE) + h * HSZ + row_) * TT + t0_ + g_ * 8,\
                        &Vs[(buf) * 4096 + R0_ * 64]);                               \
        }                                                                            \
    }

    STAGE_QV(0, 0)

    float m[4], l[4];
    f32x4 oacc[4] = {};
#pragma unroll
    for (int r = 0; r < 4; ++r) { m[r] = -INFINITY; l[r] = 0.f; }

    int cur = 0;
    for (int jt = 0; jt <= js; ++jt) {
        __syncthreads();
        if (jt < js) STAGE_QV(jt + 1, cur ^ 1)

        const u16* Qb = &Qs[cur * 4096];
        const u16* Vb = &Vs[cur * 4096];

        f32x4 sc[4] = {};
#pragma unroll
        for (int ni = 0; ni < 4; ++ni) {
            int trow = ni * 16 + (lane & 15);
#pragma unroll
            for (int kk = 0; kk < 2; ++kk) {
                int g = kk * 4 + (lane >> 4);
                short8 bq = *reinterpret_cast<const short8*>(
                    &Qb[trow * 64 + ((g ^ (trow & 7)) * 8)]);
                sc[ni] = __builtin_amdgcn_mfma_f32_16x16x32_bf16(af[kk], bq, sc[ni], 0, 0, 0);
            }
        }

        const bool diag = (jt == js);
#pragma unroll
        for (int ni = 0; ni < 4; ++ni)
#pragma unroll
            for (int r = 0; r < 4; ++r) {
                float sv = sc[ni][r] * scale;
                if (diag && (ni * 16 + (lane & 15)) > (wv * 16 + (lane >> 4) * 4 + r))
                    sv = -1e30f;
                sc[ni][r] = sv;
            }

        f32x4 pexp[4];
#pragma unroll
        for (int r = 0; r < 4; ++r) {
            float rm = fmaxf(fmaxf(sc[0][r], sc[1][r]), fmaxf(sc[2][r], sc[3][r]));
#pragma unroll
            for (int o = 1; o < 16; o <<= 1) rm = fmaxf(rm, __shfl_xor(rm, o));
            float mnew = fmaxf(m[r], rm);
            float alpha = __expf(m[r] - mnew);
            m[r] = mnew;
            float rs = 0.f;
#pragma unroll
            for (int ni = 0; ni < 4; ++ni) {
                float p = __expf(sc[ni][r] - mnew);
                pexp[ni][r] = p;
                rs += p;
            }
#pragma unroll
            for (int o = 1; o < 16; o <<= 1) rs += __shfl_xor(rs, o);
            l[r] = l[r] * alpha + rs;
#pragma unroll
            for (int dt = 0; dt < 4; ++dt) oacc[dt][r] *= alpha;
        }

#pragma unroll
        for (int ni = 0; ni < 4; ++ni)
#pragma unroll
            for (int r = 0; r < 4; ++r) {
                int sl = (lane >> 4) * 4 + r;
                int tl = ni * 16 + (lane & 15);
                Ps[wv * 1024 + sl * 64 + ((tl >> 3) ^ (sl & 7)) * 8 + (tl & 7)] = f2bf(pexp[ni][r]);
            }

        short8 pa[2];
#pragma unroll
        for (int kk = 0; kk < 2; ++kk) {
            int srow = lane & 15;
            int g = kk * 4 + (lane >> 4);
            pa[kk] = *reinterpret_cast<const short8*>(
                &Ps[wv * 1024 + srow * 64 + ((g ^ (srow & 7)) * 8)]);
        }

#pragma unroll
        for (int dt = 0; dt < 4; ++dt) {
            int drow = dt * 16 + (lane & 15);
#pragma unroll
            for (int kk = 0; kk < 2; ++kk) {
                int g = kk * 4 + (lane >> 4);
                short8 bv = *reinterpret_cast<const short8*>(
                    &Vb[drow * 64 + ((g ^ (drow & 7)) * 8)]);
                oacc[dt] = __builtin_amdgcn_mfma_f32_16x16x32_bf16(pa[kk], bv, oacc[dt], 0, 0, 0);
            }
        }
        cur ^= 1;
    }

    float invl[4];
#pragma unroll
    for (int r = 0; r < 4; ++r) invl[r] = 1.0f / l[r];
#pragma unroll
    for (int dt = 0; dt < 4; ++dt)
#pragma unroll
        for (int r = 0; r < 4; ++r) {
            int sg = s0 + wv * 16 + (lane >> 4) * 4 + r;
            aout[(size_t)(bT + sg) * EE + h * HSZ + dt * 16 + (lane & 15)] =
                oacc[dt][r] * invl[r];
        }
}

// ---------------------------------------------------------------- driver
extern "C" void kernel_launch(void* const* d_in, const int* in_sizes, int n_in,
                              void* d_out, int out_size, void* d_ws, size_t ws_size,
                              hipStream_t stream)
{
    const int*   x    = (const int*)d_in[0];
    const float* tok  = (const float*)d_in[1];
    const float* pos  = (const float*)d_in[2];
    const float* qW   = (const float*)d_in[3];
    const float* kW   = (const float*)d_in[4];
    const float* vW   = (const float*)d_in[5];
    const float* ln1w = (const float*)d_in[6];
    const float* ln1b = (const float*)d_in[7];
    const float* fc1w = (const float*)d_in[8];
    const float* fc1b = (const float*)d_in[9];
    const float* fc2w = (const float*)d_in[10];
    const float* fc2b = (const float*)d_in[11];
    const float* ln2w = (const float*)d_in[12];
    const float* ln2b = (const float*)d_in[13];
    const float* lnfw = (const float*)d_in[14];
    const float* lnfb = (const float*)d_in[15];
    const float* lmw  = (const float*)d_in[16];
    float* out = (float*)d_out;

    char* ws = (char*)d_ws;
    u16* wqkv = (u16*)ws;  ws += (size_t)LL * NQKV * EE * 2;
    u16* wfc1 = (u16*)ws;  ws += (size_t)LL * FF * EE * 2;
    u16* wfc2 = (u16*)ws;  ws += (size_t)LL * EE * FF * 2;
    u16* wlm  = (u16*)ws;  ws += (size_t)VPAD * EE * 2;
    float* h    = (float*)ws; ws += (size_t)MM * EE * 4;
    float* tmp  = (float*)ws; ws += (size_t)MM * EE * 4;
    u16* qkb = (u16*)ws;      ws += (size_t)MM * QKW * 2;
    u16* vTb = (u16*)ws;      ws += (size_t)BB * EE * TT * 2;
    u16* hb  = (u16*)ws;      ws += (size_t)MM * EE * 2;
    u16* mb  = (u16*)ws;      ws += (size_t)MM * FF * 2;

    dim3 blk(256);

    cast_kernel<<<dim3(512, LL), blk, 0, stream>>>(qW, wqkv,               (long)EE * EE, (long)NQKV * EE);
    cast_kernel<<<dim3(512, LL), blk, 0, stream>>>(kW, wqkv + EE * EE,     (long)EE * EE, (long)NQKV * EE);
    cast_kernel<<<dim3(512, LL), blk, 0, stream>>>(vW, wqkv + 2 * EE * EE, (long)EE * EE, (long)NQKV * EE);
    cast_kernel<<<dim3(2048, LL), blk, 0, stream>>>(fc1w, wfc1, (long)FF * EE, (long)FF * EE);
    cast_kernel<<<dim3(2048, LL), blk, 0, stream>>>(fc2w, wfc2, (long)EE * FF, (long)EE * FF);
    cast_kernel<<<dim3(4096, 1),  blk, 0, stream>>>(lmw,  wlm,  (long)VV * EE, (long)VV * EE);

    embed_kernel<<<MM, blk, 0, stream>>>(x, tok, pos, h, hb);

    dim3 gQKV(MM / BM, NQKV / BN);
    dim3 gF1(MM / BM, FF / BN);
    dim3 gF2(MM / BM, EE / BN);
    dim3 gV(MM / BM, VPAD / BN);
    dim3 gAttn(TT / 64, BB * HH);

    for (int l = 0; l < LL; ++l) {
        gemm_kernel<EPI_QKV, false><<<gQKV, blk, 0, stream>>>(
            hb, wqkv + (size_t)l * NQKV * EE, nullptr, qkb, vTb, NQKV, EE);
        attn_kernel<<<gAttn, blk, 0, stream>>>(qkb, vTb, tmp);
        add_ln_kernel<<<MM / 4, blk, 0, stream>>>(h, tmp, ln1w + l * EE, ln1b + l * EE, h, hb);
        gemm_kernel<EPI_GELU_BF16, false><<<gF1, blk, 0, stream>>>(
            hb, wfc1 + (size_t)l * FF * EE, fc1b + (size_t)l * FF, mb, nullptr, FF, EE);
        gemm_kernel<EPI_BIAS_F32, false><<<gF2, blk, 0, stream>>>(
            mb, wfc2 + (size_t)l * EE * FF, fc2b + (size_t)l * EE, tmp, nullptr, EE, FF);
        add_ln_kernel<<<MM / 4, blk, 0, stream>>>(h, tmp, ln2w + l * EE, ln2b + l * EE, h, hb);
    }
    add_ln_kernel<<<MM / 4, blk, 0, stream>>>(h, nullptr, lnfw, lnfb, h, hb);
    gemm_kernel<EPI_F32, true><<<gV, blk, 0, stream>>>(hb, wlm, nullptr, out, nullptr, VV, EE);
}